// Round 1
// baseline (375.596 us; speedup 1.0000x reference)
//
#include <hip/hip_runtime.h>
#include <hip/hip_bf16.h>

#define IN_F 256
#define NN   2048
#define BB   8
#define NEGV (-9.0e15f)

typedef unsigned short u16;
typedef __attribute__((ext_vector_type(8))) short short8x;   // 8 bf16 = 4 VGPRs
typedef __attribute__((ext_vector_type(4))) float float4x;   // MFMA acc

// fp32 -> bf16 bits, round-to-nearest-even
__device__ __forceinline__ u16 f2b(float f) {
    union { float f; unsigned int u; } x; x.f = f;
    unsigned int r = x.u + 0x7FFFu + ((x.u >> 16) & 1u);
    return (u16)(r >> 16);
}

__device__ __forceinline__ float logitf(float wh1v, float w, int av) {
    float e = wh1v + w;
    e = (e >= 0.f) ? e : 0.2f * e;
    return (av > 0) ? e : NEGV;
}

// ---------------------------------------------------------------------------
// prep: fused transposes (h->HbfT, lrgt1->GbfT, W1->W1T, W2->W2T) + calc_v.
// ---------------------------------------------------------------------------
__device__ __forceinline__ void transp_body(const float* __restrict__ src,
                                            u16* __restrict__ dst,
                                            int R, int C, int tid,
                                            float (*tile)[33])
{
    const int per = (R / 32) * (C / 32);
    const int b  = tid / per;
    const int tt = tid % per;
    const int jt = tt / (C / 32);
    const int ct = tt % (C / 32);
    src += (long)b * R * C;
    dst += (long)b * R * C;

    const int tx = threadIdx.x & 31, ty = threadIdx.x >> 5;
#pragma unroll
    for (int i = 0; i < 4; ++i)
        tile[ty + i * 8][tx] = src[(long)(jt * 32 + ty + i * 8) * C + ct * 32 + tx];
    __syncthreads();
#pragma unroll
    for (int i = 0; i < 4; ++i)
        dst[(long)(ct * 32 + ty + i * 8) * R + jt * 32 + tx] = f2b(tile[tx][ty + i * 8]);
}

__global__ __launch_bounds__(256) void prep(const float* __restrict__ h,
                                            const float* __restrict__ g,
                                            const float* __restrict__ W1,
                                            const float* __restrict__ W2,
                                            const float* __restrict__ a,
                                            u16* __restrict__ HbfT,
                                            u16* __restrict__ GbfT,
                                            u16* __restrict__ W1T,
                                            u16* __restrict__ W2T,
                                            float* __restrict__ v1,
                                            float* __restrict__ v2)
{
    __shared__ float tile[32][33];
    __shared__ float s1[IN_F], s2[IN_F];
    const int bid = blockIdx.x;

    if (bid < 4096) {
        transp_body(h, HbfT, NN, IN_F, bid, tile);
    } else if (bid < 8192) {
        transp_body(g, GbfT, NN, IN_F, bid - 4096, tile);
    } else if (bid < 8256) {
        transp_body(W1, W1T, IN_F, IN_F, bid - 8192, tile);
    } else if (bid < 8320) {
        transp_body(W2, W2T, IN_F, IN_F, bid - 8256, tile);
    } else {
        const int t = threadIdx.x;
        s1[t] = a[t];
        s2[t] = a[IN_F + t];
        __syncthreads();
        float acc1 = 0.f, acc2 = 0.f;
        for (int c = 0; c < IN_F; ++c) {
            float w = W1[t * IN_F + c];
            acc1 += w * s1[c];
            acc2 += w * s2[c];
        }
        v1[t] = acc1;
        v2[t] = acc2;
    }
}

// ---------------------------------------------------------------------------
// rowdots: Wh1[row] = h[row,:]·v1, Wh2[row] = h[row,:]·v2. One wave per row.
// ---------------------------------------------------------------------------
__global__ __launch_bounds__(256) void rowdots(const float* __restrict__ h,
                                               const float* __restrict__ v1,
                                               const float* __restrict__ v2,
                                               float* __restrict__ Wh1,
                                               float* __restrict__ Wh2)
{
    const int wave = threadIdx.x >> 6;
    const int lane = threadIdx.x & 63;
    const long row = (long)blockIdx.x * 4 + wave;
    const int c0 = lane * 4;

    float4 v  = *(const float4*)(h + row * IN_F + c0);
    float4 a1 = *(const float4*)(v1 + c0);
    float4 a2 = *(const float4*)(v2 + c0);

    float s1 = v.x * a1.x + v.y * a1.y + v.z * a1.z + v.w * a1.w;
    float s2 = v.x * a2.x + v.y * a2.y + v.z * a2.z + v.w * a2.w;
#pragma unroll
    for (int off = 32; off; off >>= 1) {
        s1 += __shfl_xor(s1, off, 64);
        s2 += __shfl_xor(s2, off, 64);
    }
    if (lane == 0) { Wh1[row] = s1; Wh2[row] = s2; }
}

// ---------------------------------------------------------------------------
// attn_mfma v2:
//  * batch-per-XCD blockIdx swizzle: blocks with the same (bid%8) — i.e. the
//    same XCD under round-robin dispatch — now all work on ONE batch, so the
//    HbfT/GbfT stream (2 MB/batch) fits that XCD's 4 MB L2 instead of 16 MB
//    thrashing to L3.  (bijective remap; correctness-neutral)
//  * lgkm-only barrier in the K-chunk loop: __syncthreads emits
//    s_waitcnt vmcnt(0) which drained the adj HBM prefetch every chunk.
//    Only the Afrag ds_write needs cross-wave visibility -> lgkmcnt(0).
//    All global loads here are read-only, so skipping the vmcnt drain is safe.
//  * B-fragment register double-buffering: the 4 B loads of group ks+1 are
//    issued before the 8 MFMAs of group ks (and the first group of chunk
//    k+1 is issued before the barrier, surviving it) -> MLP 4 -> ~8+.
// ---------------------------------------------------------------------------
__global__ __launch_bounds__(512, 4) void attn_mfma(
    const int* __restrict__ adj,
    const u16* __restrict__ HbfT, const u16* __restrict__ GbfT,
    const float* __restrict__ Wh1, const float* __restrict__ Wh2,
    u16* __restrict__ PH, u16* __restrict__ PG)
{
    const int t = threadIdx.x;
    const int wave = t >> 6, lane = t & 63;
    // batch-per-XCD swizzle (512 blocks, 8 XCDs -> 64 blocks = 1 batch each)
    const int bswz = ((blockIdx.x & 7) << 6) | (blockIdx.x >> 3);
    const int b = bswz >> 6;                  // 64 row-blocks per batch
    const long gi0 = (long)bswz * 32;         // global row base

    __shared__ __align__(16) u16 Afrag[2][4096];   // 2 x 8 KB
    __shared__ float sred[512];
    __shared__ float ssc[33];                      // [0..31]=1/l, [32]=wh2max

    // thread role: row rr (32), segment sg (16) -> 8 consecutive j per chunk
    const int rr = t >> 4, sg = t & 15;
    const long adjR = (gi0 + rr) * (long)NN;
    const float* wh2b = Wh2 + (long)b * NN;
    const float wh1rr = Wh1[gi0 + rr];

    // ---- per-batch max of Wh2 (8 KB, L2-hot) ----
    {
        float4 w = *(const float4*)(wh2b + t * 4);
        sred[t] = fmaxf(fmaxf(w.x, w.y), fmaxf(w.z, w.w));
    }
    __syncthreads();
    if (t < 64) {
        float v = sred[t * 8];
#pragma unroll
        for (int k = 1; k < 8; ++k) v = fmaxf(v, sred[t * 8 + k]);
#pragma unroll
        for (int off = 32; off; off >>= 1) v = fmaxf(v, __shfl_xor(v, off, 64));
        if (t == 0) ssc[32] = v;
    }
    __syncthreads();
    const float mm = wh1rr + ssc[32];
    const float mv = (mm >= 0.f) ? mm : 0.2f * mm;   // lrelu upper bound >= all logits

    // A-fragment write slot for this thread (16x16x32 A layout:
    // lane = m + 16*(k>>3), 8 k's per lane)
    const int ks0 = sg >> 2;
    const int wl  = (rr & 15) + ((sg & 3) << 4);
    const int prt = rr >> 4;
    const int aoff = ((ks0 * 2 + prt) * 64 + wl) * 8;

    float4x accH[2][2], accG[2][2];
#pragma unroll
    for (int rt = 0; rt < 2; ++rt)
#pragma unroll
        for (int ct = 0; ct < 2; ++ct) {
            accH[rt][ct] = (float4x)0.0f;
            accG[rt][ct] = (float4x)0.0f;
        }

    const int bn = lane & 15, bq = lane >> 4;
    const long hbase = (long)b * IN_F * NN;
    float lloc = 0.f;

    // per-wave B row pointers (ct=0 rows and ct=1 rows, both matrices)
    const u16* Hb0 = HbfT + hbase + (long)(wave * 32 + bn) * NN;
    const u16* Hb1 = Hb0 + 16 * (long)NN;
    const u16* Gb0 = GbfT + hbase + (long)(wave * 32 + bn) * NN;
    const u16* Gb1 = Gb0 + 16 * (long)NN;

    // prologue: load adj/Wh2 chunk 0
    int4   a0 = *(const int4*)(adj + adjR + sg * 8);
    int4   a1 = *(const int4*)(adj + adjR + sg * 8 + 4);
    float4 w0 = *(const float4*)(wh2b + sg * 8);
    float4 w1 = *(const float4*)(wh2b + sg * 8 + 4);

    // prologue: B group (kch=0, ks=0)
    short8x Bc0 = *(const short8x*)(Hb0 + bq * 8);
    short8x Bc1 = *(const short8x*)(Gb0 + bq * 8);
    short8x Bc2 = *(const short8x*)(Hb1 + bq * 8);
    short8x Bc3 = *(const short8x*)(Gb1 + bq * 8);

    for (int kch = 0; kch < 16; ++kch) {
        const int j0 = kch * 128;

        // compute unnormalized p (<= 1) from current regs
        union { short8x v; u16 u[8]; } pk;
        float p;
        p = __expf(logitf(wh1rr, w0.x, a0.x) - mv); lloc += p; pk.u[0] = f2b(p);
        p = __expf(logitf(wh1rr, w0.y, a0.y) - mv); lloc += p; pk.u[1] = f2b(p);
        p = __expf(logitf(wh1rr, w0.z, a0.z) - mv); lloc += p; pk.u[2] = f2b(p);
        p = __expf(logitf(wh1rr, w0.w, a0.w) - mv); lloc += p; pk.u[3] = f2b(p);
        p = __expf(logitf(wh1rr, w1.x, a1.x) - mv); lloc += p; pk.u[4] = f2b(p);
        p = __expf(logitf(wh1rr, w1.y, a1.y) - mv); lloc += p; pk.u[5] = f2b(p);
        p = __expf(logitf(wh1rr, w1.z, a1.z) - mv); lloc += p; pk.u[6] = f2b(p);
        p = __expf(logitf(wh1rr, w1.w, a1.w) - mv); lloc += p; pk.u[7] = f2b(p);

        // prefetch next chunk's adj/Wh2 (survives the relaxed barrier below;
        // cover = this chunk's full MFMA phase)
        if (kch < 15) {
            const long o = adjR + (kch + 1) * 128 + sg * 8;
            const int  w = (kch + 1) * 128 + sg * 8;
            a0 = *(const int4*)(adj + o);
            a1 = *(const int4*)(adj + o + 4);
            w0 = *(const float4*)(wh2b + w);
            w1 = *(const float4*)(wh2b + w + 4);
        }

        *(short8x*)&Afrag[kch & 1][aoff] = pk.v;
        // lgkm-only barrier: make the Afrag ds_write visible without draining
        // the in-flight global prefetches (adj/Wh2/B) the way __syncthreads'
        // s_waitcnt vmcnt(0) would.
        asm volatile("s_waitcnt lgkmcnt(0)\n\ts_barrier" ::: "memory");

        const u16* ab = Afrag[kch & 1];
        const int jb = j0 + bq * 8;
#pragma unroll
        for (int ks = 0; ks < 4; ++ks) {
            short8x A0 = *(const short8x*)&ab[((ks * 2 + 0) * 64 + lane) * 8];
            short8x A1 = *(const short8x*)&ab[((ks * 2 + 1) * 64 + lane) * 8];
            // issue next B group before consuming the current one
            // (ks=3 issues chunk kch+1's ks=0 group; last chunk re-loads jb, dead)
            const int jn = (ks < 3) ? (jb + (ks + 1) * 32)
                                    : ((kch < 15) ? (jb + 128) : jb);
            short8x Bn0 = *(const short8x*)(Hb0 + jn);
            short8x Bn1 = *(const short8x*)(Gb0 + jn);
            short8x Bn2 = *(const short8x*)(Hb1 + jn);
            short8x Bn3 = *(const short8x*)(Gb1 + jn);

            accH[0][0] = __builtin_amdgcn_mfma_f32_16x16x32_bf16(A0, Bc0, accH[0][0], 0, 0, 0);
            accH[1][0] = __builtin_amdgcn_mfma_f32_16x16x32_bf16(A1, Bc0, accH[1][0], 0, 0, 0);
            accG[0][0] = __builtin_amdgcn_mfma_f32_16x16x32_bf16(A0, Bc1, accG[0][0], 0, 0, 0);
            accG[1][0] = __builtin_amdgcn_mfma_f32_16x16x32_bf16(A1, Bc1, accG[1][0], 0, 0, 0);
            accH[0][1] = __builtin_amdgcn_mfma_f32_16x16x32_bf16(A0, Bc2, accH[0][1], 0, 0, 0);
            accH[1][1] = __builtin_amdgcn_mfma_f32_16x16x32_bf16(A1, Bc2, accH[1][1], 0, 0, 0);
            accG[0][1] = __builtin_amdgcn_mfma_f32_16x16x32_bf16(A0, Bc3, accG[0][1], 0, 0, 0);
            accG[1][1] = __builtin_amdgcn_mfma_f32_16x16x32_bf16(A1, Bc3, accG[1][1], 0, 0, 0);

            Bc0 = Bn0; Bc1 = Bn1; Bc2 = Bn2; Bc3 = Bn3;
        }
    }

    // ---- reduce l per row, invert ----
    __syncthreads();             // sred free (wh2max phase long done); Afrag idle
    sred[rr * 16 + sg] = lloc;
    __syncthreads();
    if (t < 32) {
        float v = sred[t * 16];
#pragma unroll
        for (int k = 1; k < 16; ++k) v += sred[t * 16 + k];
        ssc[t] = 1.0f / v;       // v > 0 always (~half the j's unmasked)
    }
    __syncthreads();

    // ---- scale by 1/l and store (C-layout: col=lane&15, row=(lane>>4)*4+reg)
#pragma unroll
    for (int rt = 0; rt < 2; ++rt)
#pragma unroll
        for (int ct = 0; ct < 2; ++ct) {
            const int c = wave * 32 + ct * 16 + bn;
#pragma unroll
            for (int reg = 0; reg < 4; ++reg) {
                const int rl = rt * 16 + bq * 4 + reg;
                const float il = ssc[rl];
                const long row = gi0 + rl;
                PH[row * IN_F + c] = f2b(accH[rt][ct][reg] * il);
                PG[row * IN_F + c] = f2b(accG[rt][ct][reg] * il);
            }
        }
}

// ---------------------------------------------------------------------------
// epi2: both epilogue GEMMs in one launch.
// blocks [0,512): out0 = ELU(PH @ W1); blocks [512,1024): out1 = ELU(PG @ W2)
// ---------------------------------------------------------------------------
__global__ __launch_bounds__(256) void epi2(const u16* __restrict__ PH,
                                            const u16* __restrict__ PG,
                                            const u16* __restrict__ W1T,
                                            const u16* __restrict__ W2T,
                                            float* __restrict__ out)
{
    int bid = blockIdx.x;
    const u16* X;
    const u16* WT;
    float* o;
    if (bid < 512) { X = PH; WT = W1T; o = out; }
    else           { X = PG; WT = W2T; o = out + (long)BB * NN * IN_F; bid -= 512; }

    const int t = threadIdx.x;
    const int wave = t >> 6, lane = t & 63;
    const long i0 = (long)bid * 32;

    __shared__ __align__(16) u16 Afrag[8 * 2 * 64 * 8];   // 16 KB

    const int m = t >> 3, ks0 = t & 7, rt0 = m >> 4, lm = m & 15;
    const u16* xp = X + (i0 + m) * IN_F + ks0 * 32;
#pragma unroll
    for (int q = 0; q < 4; ++q) {
        short8x v = *(const short8x*)(xp + q * 8);
        *(short8x*)&Afrag[((ks0 * 2 + rt0) * 64 + lm + q * 16) * 8] = v;
    }
    __syncthreads();

    float4x acc[2][4];
#pragma unroll
    for (int rt = 0; rt < 2; ++rt)
#pragma unroll
        for (int ct = 0; ct < 4; ++ct) acc[rt][ct] = (float4x)0.0f;

    const int bn = lane & 15, bq = lane >> 4;
#pragma unroll
    for (int ks = 0; ks < 8; ++ks) {
        short8x A0 = *(const short8x*)&Afrag[((ks * 2 + 0) * 64 + lane) * 8];
        short8x A1 = *(const short8x*)&Afrag[((ks * 2 + 1) * 64 + lane) * 8];
#pragma unroll
        for (int ct = 0; ct < 4; ++ct) {
            const int n = wave * 64 + ct * 16 + bn;
            short8x Bw = *(const short8x*)(WT + n * IN_F + ks * 32 + bq * 8);
            acc[0][ct] = __builtin_amdgcn_mfma_f32_16x16x32_bf16(A0, Bw, acc[0][ct], 0, 0, 0);
            acc[1][ct] = __builtin_amdgcn_mfma_f32_16x16x32_bf16(A1, Bw, acc[1][ct], 0, 0, 0);
        }
    }

#pragma unroll
    for (int rt = 0; rt < 2; ++rt)
#pragma unroll
        for (int ct = 0; ct < 4; ++ct) {
            const int n = wave * 64 + ct * 16 + bn;
#pragma unroll
            for (int reg = 0; reg < 4; ++reg) {
                const long row = i0 + rt * 16 + bq * 4 + reg;
                float v = acc[rt][ct][reg];
                v = (v > 0.f) ? v : (__expf(v) - 1.f);   // ELU
                o[row * IN_F + n] = v;
            }
        }
}

// ---------------------------------------------------------------------------
extern "C" void kernel_launch(void* const* d_in, const int* in_sizes, int n_in,
                              void* d_out, int out_size, void* d_ws, size_t ws_size,
                              hipStream_t stream)
{
    int ih = -1, ig = -1, iadj = -1, iw1 = -1, iw2 = -1, ia = -1;
    for (int i = 0; i < n_in; ++i) {
        int s = in_sizes[i];
        if      (s == BB * NN * NN)   { if (iadj < 0) iadj = i; }
        else if (s == BB * NN * IN_F) { if (ih < 0) ih = i; else if (ig < 0) ig = i; }
        else if (s == IN_F * IN_F)    { if (iw1 < 0) iw1 = i; else if (iw2 < 0) iw2 = i; }
        else if (s == 2 * IN_F)       { if (ia < 0) ia = i; }
    }
    if (ih < 0 || ig < 0 || iadj < 0 || iw1 < 0 || iw2 < 0 || ia < 0) {
        ih = 0; iadj = 1; ig = 2; iw1 = 3; iw2 = 4; ia = 5;
    }
    const float* h     = (const float*)d_in[ih];
    const int*   adj   = (const int*)  d_in[iadj];
    const float* lrgt1 = (const float*)d_in[ig];
    const float* W1    = (const float*)d_in[iw1];
    const float* W2    = (const float*)d_in[iw2];
    const float* a     = (const float*)d_in[ia];
    float* out = (float*)d_out;

    // ws layout — 33,949,696 B total (<= proven-available 34,212,096 B)
    float* ws   = (float*)d_ws;
    float* v1   = ws;                       // 256
    float* v2   = v1 + IN_F;                // 256
    float* Wh1  = v2 + IN_F;                // 16384
    float* Wh2  = Wh1 + BB * NN;            // 16384
    u16* W1T  = (u16*)(Wh2 + BB * NN);      // 65536 bf16
    u16* W2T  = W1T + IN_F * IN_F;          // 65536
    u16* HbfT = W2T + IN_F * IN_F;          // 8*256*2048
    u16* GbfT = HbfT + (long)BB * IN_F * NN;
    u16* PH   = GbfT + (long)BB * IN_F * NN;
    u16* PG   = PH + (long)BB * NN * IN_F;

    const int nrows = BB * NN;

    prep     <<<8321,        256, 0, stream>>>(h, lrgt1, W1, W2, a,
                                               HbfT, GbfT, W1T, W2T, v1, v2);
    rowdots  <<<nrows / 4,   256, 0, stream>>>(h, v1, v2, Wh1, Wh2);
    attn_mfma<<<nrows / 32,  512, 0, stream>>>(adj, HbfT, GbfT, Wh1, Wh2, PH, PG);
    epi2     <<<2 * nrows / 32, 256, 0, stream>>>(PH, PG, W1T, W2T, out);
}

// Round 2
// 309.731 us; speedup vs baseline: 1.2127x; 1.2127x over previous
//
#include <hip/hip_runtime.h>
#include <hip/hip_bf16.h>

#define IN_F 256
#define NN   2048
#define BB   8
#define NEGV (-9.0e15f)

typedef unsigned short u16;
typedef __attribute__((ext_vector_type(8))) short short8x;   // 8 bf16 = 4 VGPRs
typedef __attribute__((ext_vector_type(4))) float float4x;   // MFMA acc

// fp32 -> bf16 bits, round-to-nearest-even
__device__ __forceinline__ u16 f2b(float f) {
    union { float f; unsigned int u; } x; x.f = f;
    unsigned int r = x.u + 0x7FFFu + ((x.u >> 16) & 1u);
    return (u16)(r >> 16);
}

// ---------------------------------------------------------------------------
// prep: fused transposes (h->HbfT, lrgt1->GbfT, W1->W1T, W2->W2T) + calc_v.
// ---------------------------------------------------------------------------
__device__ __forceinline__ void transp_body(const float* __restrict__ src,
                                            u16* __restrict__ dst,
                                            int R, int C, int tid,
                                            float (*tile)[33])
{
    const int per = (R / 32) * (C / 32);
    const int b  = tid / per;
    const int tt = tid % per;
    const int jt = tt / (C / 32);
    const int ct = tt % (C / 32);
    src += (long)b * R * C;
    dst += (long)b * R * C;

    const int tx = threadIdx.x & 31, ty = threadIdx.x >> 5;
#pragma unroll
    for (int i = 0; i < 4; ++i)
        tile[ty + i * 8][tx] = src[(long)(jt * 32 + ty + i * 8) * C + ct * 32 + tx];
    __syncthreads();
#pragma unroll
    for (int i = 0; i < 4; ++i)
        dst[(long)(ct * 32 + ty + i * 8) * R + jt * 32 + tx] = f2b(tile[tx][ty + i * 8]);
}

__global__ __launch_bounds__(256) void prep(const float* __restrict__ h,
                                            const float* __restrict__ g,
                                            const float* __restrict__ W1,
                                            const float* __restrict__ W2,
                                            const float* __restrict__ a,
                                            u16* __restrict__ HbfT,
                                            u16* __restrict__ GbfT,
                                            u16* __restrict__ W1T,
                                            u16* __restrict__ W2T,
                                            float* __restrict__ v1,
                                            float* __restrict__ v2)
{
    __shared__ float tile[32][33];
    __shared__ float s1[IN_F], s2[IN_F];
    const int bid = blockIdx.x;

    if (bid < 4096) {
        transp_body(h, HbfT, NN, IN_F, bid, tile);
    } else if (bid < 8192) {
        transp_body(g, GbfT, NN, IN_F, bid - 4096, tile);
    } else if (bid < 8256) {
        transp_body(W1, W1T, IN_F, IN_F, bid - 8192, tile);
    } else if (bid < 8320) {
        transp_body(W2, W2T, IN_F, IN_F, bid - 8256, tile);
    } else {
        const int t = threadIdx.x;
        s1[t] = a[t];
        s2[t] = a[IN_F + t];
        __syncthreads();
        float acc1 = 0.f, acc2 = 0.f;
        for (int c = 0; c < IN_F; ++c) {
            float w = W1[t * IN_F + c];
            acc1 += w * s1[c];
            acc2 += w * s2[c];
        }
        v1[t] = acc1;
        v2[t] = acc2;
    }
}

// ---------------------------------------------------------------------------
// rowdots: Wh1[row] = h[row,:]·v1, Wh2[row] = h[row,:]·v2. One wave per row.
// ---------------------------------------------------------------------------
__global__ __launch_bounds__(256) void rowdots(const float* __restrict__ h,
                                               const float* __restrict__ v1,
                                               const float* __restrict__ v2,
                                               float* __restrict__ Wh1,
                                               float* __restrict__ Wh2)
{
    const int wave = threadIdx.x >> 6;
    const int lane = threadIdx.x & 63;
    const long row = (long)blockIdx.x * 4 + wave;
    const int c0 = lane * 4;

    float4 v  = *(const float4*)(h + row * IN_F + c0);
    float4 a1 = *(const float4*)(v1 + c0);
    float4 a2 = *(const float4*)(v2 + c0);

    float s1 = v.x * a1.x + v.y * a1.y + v.z * a1.z + v.w * a1.w;
    float s2 = v.x * a2.x + v.y * a2.y + v.z * a2.z + v.w * a2.w;
#pragma unroll
    for (int off = 32; off; off >>= 1) {
        s1 += __shfl_xor(s1, off, 64);
        s2 += __shfl_xor(s2, off, 64);
    }
    if (lane == 0) { Wh1[row] = s1; Wh2[row] = s2; }
}

// ---------------------------------------------------------------------------
// attn_mfma v3: BM=64 restructure.
//  * 256 blocks (1/CU), 8 waves; each wave owns a 64-row x 64-col output
//    slice -> acc[4][4] fragments (64 VGPR).  Per K-step of 32: 4 A ds_reads
//    + 4 B global loads feed 16 MFMAs (2x the MFMA-per-load intensity of the
//    BM=32 version), and total B-panel L2 traffic halves (1 GB -> 512 MB).
//  * batch-per-XCD swizzle: 32 blocks/XCD = exactly one batch -> B panel
//    (2 MB) is L2-resident per XCD.
//  * adj/Wh2 prefetched one full K-chunk (128) ahead via parity-unrolled
//    register double-buffers (macro ping-pong, no register copies, so the
//    vmcnt wait for the prefetch lands AFTER the MFMA phase).
//  * A/B fragments ping-pong one K-step ahead; lgkm-only barrier keeps all
//    global prefetches in flight across the chunk barrier.
// ---------------------------------------------------------------------------
#define KSTEP(ksv, BC, BN_, AC, AN_, do_a, jnxt)                              \
    {                                                                         \
        if (do_a) {                                                           \
            _Pragma("unroll") for (int rt = 0; rt < 4; ++rt)                  \
                AN_[rt] = *(const short8x*)&ab[(((ksv) + 1) * 4 + rt) * 512 + lane * 8]; \
        }                                                                     \
        _Pragma("unroll") for (int ct = 0; ct < 4; ++ct)                      \
            BN_[ct] = *(const short8x*)(Bp + ct * 16 * NN + (jnxt));          \
        _Pragma("unroll") for (int rt = 0; rt < 4; ++rt)                      \
            _Pragma("unroll") for (int ct = 0; ct < 4; ++ct)                  \
                acc[rt][ct] = __builtin_amdgcn_mfma_f32_16x16x32_bf16(AC[rt], BC[ct], acc[rt][ct], 0, 0, 0); \
    }

#define CHUNK(KCH, ADJC, W4C, ADJN, W4N)                                      \
    {                                                                         \
        const int j0 = (KCH) * 128;                                           \
        if ((KCH) < 15) {                                                     \
            const int jn0 = j0 + 128 + sg * 16;                               \
            _Pragma("unroll") for (int u = 0; u < 4; ++u) {                   \
                W4N[u]  = *(const float4*)(wh2b + jn0 + u * 4);               \
                ADJN[u] = *(const int4*)(adj + adjR + jn0 + u * 4);           \
            }                                                                 \
        }                                                                     \
        union { short8x v; u16 e[8]; } pk0, pk1;                              \
        _Pragma("unroll") for (int u = 0; u < 4; ++u) {                       \
            const float wv4[4] = {W4C[u].x, W4C[u].y, W4C[u].z, W4C[u].w};    \
            const int   av4[4] = {ADJC[u].x, ADJC[u].y, ADJC[u].z, ADJC[u].w};\
            _Pragma("unroll") for (int c = 0; c < 4; ++c) {                   \
                float x = wh1rr + wv4[c];                                     \
                float e = fmaxf(x, 0.2f * x);                                 \
                float p = __expf(e - mv);                                     \
                p = (av4[c] > 0) ? p : 0.0f;                                  \
                lloc += p;                                                    \
                u16 fv = f2b(p);                                              \
                if (u < 2) pk0.e[u * 4 + c] = fv;                             \
                else       pk1.e[(u - 2) * 4 + c] = fv;                       \
            }                                                                 \
        }                                                                     \
        u16* ab = &Afrag[(KCH) & 1][0];                                       \
        *(short8x*)&ab[wbase0]       = pk0.v;                                 \
        *(short8x*)&ab[wbase0 + 128] = pk1.v;                                 \
        asm volatile("s_waitcnt lgkmcnt(0)\n\ts_barrier" ::: "memory");       \
        _Pragma("unroll") for (int rt = 0; rt < 4; ++rt)                      \
            A0[rt] = *(const short8x*)&ab[rt * 512 + lane * 8];               \
        KSTEP(0, B0, B1, A0, A1, 1, j0 + 1 * 32 + bq8)                        \
        KSTEP(1, B1, B0, A1, A0, 1, j0 + 2 * 32 + bq8)                        \
        KSTEP(2, B0, B1, A0, A1, 1, j0 + 3 * 32 + bq8)                        \
        KSTEP(3, B1, B0, A1, A0, 0, (((KCH) < 15) ? (j0 + 128) : j0) + bq8)   \
    }

__global__ __launch_bounds__(512, 2) void attn_mfma(
    const int* __restrict__ adj,
    const u16* __restrict__ HbfT, const u16* __restrict__ GbfT,
    const float* __restrict__ Wh1, const float* __restrict__ Wh2,
    u16* __restrict__ PH, u16* __restrict__ PG)
{
    const int t = threadIdx.x;
    const int wave = t >> 6, lane = t & 63;
    // batch-per-XCD swizzle: 256 blocks / 8 XCDs -> 32 blocks = 1 batch each
    const int bswz = ((blockIdx.x & 7) << 5) | (blockIdx.x >> 3);
    const int b = bswz >> 5;                  // 32 row-blocks per batch
    const long gi0 = (long)bswz * 64;         // global row base (BM=64)

    __shared__ __align__(16) u16 Afrag[2][8192];   // 2 x 16 KB (4 ksteps x 4 rt)
    __shared__ float sred[512];
    __shared__ float ssc[65];                      // [0..63]=1/l, [64]=wh2max

    // p-compute role: row rr (64 rows), segment sg (8) -> 16 consecutive j
    const int rr = t >> 3, sg = t & 7;
    const long adjR = (gi0 + rr) * (long)NN;
    const float* wh2b = Wh2 + (long)b * NN;
    const float wh1rr = Wh1[gi0 + rr];

    // ---- per-batch max of Wh2 (8 KB, L2-hot) ----
    {
        float4 w = *(const float4*)(wh2b + t * 4);
        sred[t] = fmaxf(fmaxf(w.x, w.y), fmaxf(w.z, w.w));
    }
    __syncthreads();
    if (t < 64) {
        float v = sred[t * 8];
#pragma unroll
        for (int k = 1; k < 8; ++k) v = fmaxf(v, sred[t * 8 + k]);
#pragma unroll
        for (int off = 32; off; off >>= 1) v = fmaxf(v, __shfl_xor(v, off, 64));
        if (t == 0) ssc[64] = v;
    }
    __syncthreads();
    const float mm = wh1rr + ssc[64];
    const float mv = (mm >= 0.f) ? mm : 0.2f * mm;   // lrelu upper bound >= all logits

    // A-fragment write slot: thread (rr, sg) covers k_local = sg*16 + e,
    // fragment (kstep = sg>>1, rt = rr>>4), lane = (rr&15) + 16*q,
    // q = 2*(sg&1) + (e>>3).  Two short8x writes at +0 / +128 u16.
    const int wbase0 = ((sg >> 1) * 4 + (rr >> 4)) * 512
                     + ((rr & 15) + 16 * (2 * (sg & 1))) * 8;

    float4x acc[4][4];
#pragma unroll
    for (int rt = 0; rt < 4; ++rt)
#pragma unroll
        for (int ct = 0; ct < 4; ++ct) acc[rt][ct] = (float4x)0.0f;

    const int bn = lane & 15, bq = lane >> 4, bq8 = bq * 8;
    const long hbase = (long)b * IN_F * NN;
    // wave -> matrix + 64-col slice: waves 0-3 = H cols, 4-7 = G cols
    const u16* Bp = ((wave < 4) ? HbfT : GbfT) + hbase
                  + (long)((wave & 3) * 64 + bn) * NN;

    float lloc = 0.f;

    // register double-buffers (ping-pong, all statically indexed)
    short8x A0[4], A1[4], B0[4], B1[4];
    int4   adjA[4], adjB[4];
    float4 w4A[4], w4B[4];

    // prologue: adj/Wh2 chunk 0, B group (kch=0, ks=0)
#pragma unroll
    for (int u = 0; u < 4; ++u) {
        adjA[u] = *(const int4*)(adj + adjR + sg * 16 + u * 4);
        w4A[u]  = *(const float4*)(wh2b + sg * 16 + u * 4);
        adjB[u] = adjA[u];
        w4B[u]  = w4A[u];
    }
#pragma unroll
    for (int ct = 0; ct < 4; ++ct)
        B0[ct] = *(const short8x*)(Bp + ct * 16 * NN + bq8);

    for (int kp = 0; kp < 8; ++kp) {
        CHUNK(kp * 2,     adjA, w4A, adjB, w4B)
        CHUNK(kp * 2 + 1, adjB, w4B, adjA, w4A)
    }

    // ---- reduce l per row (8 partials/row), invert ----
    sred[t] = lloc;
    __syncthreads();
    if (t < 64) {
        float v = sred[t * 8];
#pragma unroll
        for (int k = 1; k < 8; ++k) v += sred[t * 8 + k];
        ssc[t] = 1.0f / v;       // v > 0 always (~half the j's unmasked)
    }
    __syncthreads();

    // ---- scale by 1/l and store (C-layout: col=lane&15, row=(lane>>4)*4+reg)
    u16* dst = (wave < 4) ? PH : PG;
    const int colb = (wave & 3) * 64;
#pragma unroll
    for (int rt = 0; rt < 4; ++rt)
#pragma unroll
        for (int ct = 0; ct < 4; ++ct) {
            const int c = colb + ct * 16 + bn;
#pragma unroll
            for (int reg = 0; reg < 4; ++reg) {
                const int rl = rt * 16 + bq * 4 + reg;
                const float il = ssc[rl];
                const long row = gi0 + rl;
                dst[row * IN_F + c] = f2b(acc[rt][ct][reg] * il);
            }
        }
}

// ---------------------------------------------------------------------------
// epi2: both epilogue GEMMs in one launch.
// blocks [0,512): out0 = ELU(PH @ W1); blocks [512,1024): out1 = ELU(PG @ W2)
// ---------------------------------------------------------------------------
__global__ __launch_bounds__(256) void epi2(const u16* __restrict__ PH,
                                            const u16* __restrict__ PG,
                                            const u16* __restrict__ W1T,
                                            const u16* __restrict__ W2T,
                                            float* __restrict__ out)
{
    int bid = blockIdx.x;
    const u16* X;
    const u16* WT;
    float* o;
    if (bid < 512) { X = PH; WT = W1T; o = out; }
    else           { X = PG; WT = W2T; o = out + (long)BB * NN * IN_F; bid -= 512; }

    const int t = threadIdx.x;
    const int wave = t >> 6, lane = t & 63;
    const long i0 = (long)bid * 32;

    __shared__ __align__(16) u16 Afrag[8 * 2 * 64 * 8];   // 16 KB

    const int m = t >> 3, ks0 = t & 7, rt0 = m >> 4, lm = m & 15;
    const u16* xp = X + (i0 + m) * IN_F + ks0 * 32;
#pragma unroll
    for (int q = 0; q < 4; ++q) {
        short8x v = *(const short8x*)(xp + q * 8);
        *(short8x*)&Afrag[((ks0 * 2 + rt0) * 64 + lm + q * 16) * 8] = v;
    }
    __syncthreads();

    float4x acc[2][4];
#pragma unroll
    for (int rt = 0; rt < 2; ++rt)
#pragma unroll
        for (int ct = 0; ct < 4; ++ct) acc[rt][ct] = (float4x)0.0f;

    const int bn = lane & 15, bq = lane >> 4;
#pragma unroll
    for (int ks = 0; ks < 8; ++ks) {
        short8x A0 = *(const short8x*)&Afrag[((ks * 2 + 0) * 64 + lane) * 8];
        short8x A1 = *(const short8x*)&Afrag[((ks * 2 + 1) * 64 + lane) * 8];
#pragma unroll
        for (int ct = 0; ct < 4; ++ct) {
            const int n = wave * 64 + ct * 16 + bn;
            short8x Bw = *(const short8x*)(WT + n * IN_F + ks * 32 + bq * 8);
            acc[0][ct] = __builtin_amdgcn_mfma_f32_16x16x32_bf16(A0, Bw, acc[0][ct], 0, 0, 0);
            acc[1][ct] = __builtin_amdgcn_mfma_f32_16x16x32_bf16(A1, Bw, acc[1][ct], 0, 0, 0);
        }
    }

#pragma unroll
    for (int rt = 0; rt < 2; ++rt)
#pragma unroll
        for (int ct = 0; ct < 4; ++ct) {
            const int n = wave * 64 + ct * 16 + bn;
#pragma unroll
            for (int reg = 0; reg < 4; ++reg) {
                const long row = i0 + rt * 16 + bq * 4 + reg;
                float v = acc[rt][ct][reg];
                v = (v > 0.f) ? v : (__expf(v) - 1.f);   // ELU
                o[row * IN_F + n] = v;
            }
        }
}

// ---------------------------------------------------------------------------
extern "C" void kernel_launch(void* const* d_in, const int* in_sizes, int n_in,
                              void* d_out, int out_size, void* d_ws, size_t ws_size,
                              hipStream_t stream)
{
    int ih = -1, ig = -1, iadj = -1, iw1 = -1, iw2 = -1, ia = -1;
    for (int i = 0; i < n_in; ++i) {
        int s = in_sizes[i];
        if      (s == BB * NN * NN)   { if (iadj < 0) iadj = i; }
        else if (s == BB * NN * IN_F) { if (ih < 0) ih = i; else if (ig < 0) ig = i; }
        else if (s == IN_F * IN_F)    { if (iw1 < 0) iw1 = i; else if (iw2 < 0) iw2 = i; }
        else if (s == 2 * IN_F)       { if (ia < 0) ia = i; }
    }
    if (ih < 0 || ig < 0 || iadj < 0 || iw1 < 0 || iw2 < 0 || ia < 0) {
        ih = 0; iadj = 1; ig = 2; iw1 = 3; iw2 = 4; ia = 5;
    }
    const float* h     = (const float*)d_in[ih];
    const int*   adj   = (const int*)  d_in[iadj];
    const float* lrgt1 = (const float*)d_in[ig];
    const float* W1    = (const float*)d_in[iw1];
    const float* W2    = (const float*)d_in[iw2];
    const float* a     = (const float*)d_in[ia];
    float* out = (float*)d_out;

    // ws layout — 33,949,696 B total (<= proven-available 34,212,096 B)
    float* ws   = (float*)d_ws;
    float* v1   = ws;                       // 256
    float* v2   = v1 + IN_F;                // 256
    float* Wh1  = v2 + IN_F;                // 16384
    float* Wh2  = Wh1 + BB * NN;            // 16384
    u16* W1T  = (u16*)(Wh2 + BB * NN);      // 65536 bf16
    u16* W2T  = W1T + IN_F * IN_F;          // 65536
    u16* HbfT = W2T + IN_F * IN_F;          // 8*256*2048
    u16* GbfT = HbfT + (long)BB * IN_F * NN;
    u16* PH   = GbfT + (long)BB * IN_F * NN;
    u16* PG   = PH + (long)BB * NN * IN_F;

    const int nrows = BB * NN;

    prep     <<<8321,        256, 0, stream>>>(h, lrgt1, W1, W2, a,
                                               HbfT, GbfT, W1T, W2T, v1, v2);
    rowdots  <<<nrows / 4,   256, 0, stream>>>(h, v1, v2, Wh1, Wh2);
    attn_mfma<<<nrows / 64,  512, 0, stream>>>(adj, HbfT, GbfT, Wh1, Wh2, PH, PG);
    epi2     <<<2 * nrows / 32, 256, 0, stream>>>(PH, PG, W1T, W2T, out);
}